// Round 1
// baseline (144.990 us; speedup 1.0000x reference)
//
#include <hip/hip_runtime.h>
#include <math.h>

#define KBINS 16
#define HID 16

// ln(0.02)
#define LN_SIGMA1 (-3.912023005428146f)

__global__ __launch_bounds__(256) void bfn_kernel(
    const float* __restrict__ mu,
    const float* __restrict__ t,
    const float* __restrict__ W1,   // [2, 16] row-major
    const float* __restrict__ b1,   // [16]
    const float* __restrict__ W2,   // [16, 2] row-major
    const float* __restrict__ b2,   // [2]
    float* __restrict__ out,        // [B, D, 16]
    int D)
{
    const int b = blockIdx.y;                       // batch row (uniform per block)
    const int d = blockIdx.x * blockDim.x + threadIdx.x;
    if (d >= D) return;

    // ---- wave-uniform per-row constants (scalar path) ----
    const float tb = t[b];
    const float e2t   = expf(2.0f * tb * LN_SIGMA1);     // 0.02^(2t) = 1 - gamma
    const float gamma = -expm1f(2.0f * tb * LN_SIGMA1);  // 1 - 0.02^(2t), no cancellation
    const float inv_gamma = 1.0f / gamma;
    const float var_scale = sqrtf(e2t / gamma);
    const bool  tiny_t = (tb < 1e-6f);

    // Fold t into layer-1 bias: c1[h] = t*W1[1][h] + b1[h]
    float w1a[HID], c1[HID], w20[HID], w21[HID];
#pragma unroll
    for (int i = 0; i < HID; ++i) {
        w1a[i] = W1[i];
        c1[i]  = fmaf(tb, W1[HID + i], b1[i]);
        w20[i] = W2[2 * i];
        w21[i] = W2[2 * i + 1];
    }
    const float bias0 = b2[0], bias1 = b2[1];

    // ---- per-element ----
    const float m = mu[(size_t)b * D + d];

    // MLP: pre = m*W1[0] + (t*W1[1]+b1); gelu (tanh approx, matches jax.nn.gelu default)
    float o0 = bias0, o1 = bias1;
#pragma unroll
    for (int i = 0; i < HID; ++i) {
        float pre = fmaf(m, w1a[i], c1[i]);
        float u = 0.7978845608028654f * fmaf(0.044715f * pre, pre * pre, pre);
        // tanh(u) = 1 - 2/(exp(2u)+1), hardware exp
        float th = 1.0f - 2.0f / (__expf(2.0f * u) + 1.0f);
        float h = 0.5f * pre * (1.0f + th);
        o0 = fmaf(h, w20[i], o0);
        o1 = fmaf(h, w21[i], o1);
    }

    float mu_x = fmaf(m, inv_gamma, -var_scale * o0);
    float lse = fminf(fmaxf(o1, -10.0f), 10.0f);
    float sigma_x = fmaxf(var_scale * __expf(lse), 0.02f);
    if (tiny_t) { mu_x = 0.0f; sigma_x = 1.0f; }

    const float inv = 0.70710678118654752f / sigma_x;   // 1/(sigma*sqrt(2))

    // 17 bin boundaries at j/8 - 1; boundary 0 -> 0, boundary 16 -> 1.
    float cdf[KBINS + 1];
    cdf[0] = 0.0f;
    cdf[KBINS] = 1.0f;
#pragma unroll
    for (int j = 1; j < KBINS; ++j) {
        float bj = (float)j * 0.125f - 1.0f;
        cdf[j] = 0.5f * (1.0f + erff((bj - mu_x) * inv));
    }

    float res[KBINS];
#pragma unroll
    for (int k = 0; k < KBINS; ++k) res[k] = cdf[k + 1] - cdf[k];

    float4* op = (float4*)(out + ((size_t)b * D + d) * KBINS);
#pragma unroll
    for (int q = 0; q < 4; ++q) {
        op[q] = make_float4(res[4 * q], res[4 * q + 1], res[4 * q + 2], res[4 * q + 3]);
    }
}

extern "C" void kernel_launch(void* const* d_in, const int* in_sizes, int n_in,
                              void* d_out, int out_size, void* d_ws, size_t ws_size,
                              hipStream_t stream) {
    const float* mu = (const float*)d_in[0];
    const float* t  = (const float*)d_in[1];
    const float* W1 = (const float*)d_in[2];
    const float* b1 = (const float*)d_in[3];
    const float* W2 = (const float*)d_in[4];
    const float* b2 = (const float*)d_in[5];
    float* out = (float*)d_out;

    const int B = in_sizes[1];          // t is [B,1]
    const int D = in_sizes[0] / B;      // mu is [B,D]

    dim3 block(256);
    dim3 grid((D + 255) / 256, B);
    bfn_kernel<<<grid, block, 0, stream>>>(mu, t, W1, b1, W2, b2, out, D);
}

// Round 2
// 125.765 us; speedup vs baseline: 1.1529x; 1.1529x over previous
//
#include <hip/hip_runtime.h>
#include <math.h>

#define KBINS 16
#define HID 16
// ln(0.02)
#define LN_SIGMA1 (-3.912023005428146f)

// Force a wave-uniform value into an SGPR (weights are uniform per block).
__device__ __forceinline__ float to_sgpr(float x) {
    return __int_as_float(__builtin_amdgcn_readfirstlane(__float_as_int(x)));
}

__global__ __launch_bounds__(256, 4) void bfn_kernel(
    const float* __restrict__ mu,
    const float* __restrict__ t,
    const float* __restrict__ W1,   // [2,16]
    const float* __restrict__ b1,   // [16]
    const float* __restrict__ W2,   // [16,2]
    const float* __restrict__ b2,   // [2]
    float* __restrict__ out,        // [B,D,16]
    int D)
{
    // 256 rows x 20 words (80 B row stride: 16B-aligned, conflict-free for
    // both the b128 writes and the strided b128 transpose reads).
    __shared__ float lds[256 * 20];

    const int b   = blockIdx.y;
    const int tid = threadIdx.x;
    const int d0  = blockIdx.x * 256;
    const int d   = d0 + tid;
    const bool valid = (d < D);

    // ---- wave-uniform per-row constants ----
    const float tb    = t[b];
    const float gamma = -expm1f(2.0f * tb * LN_SIGMA1);  // 1 - 0.02^(2t), no cancellation
    const float e2t   = 1.0f - gamma;                    // 0.02^(2t)
    const float inv_gamma = 1.0f / gamma;
    const float var_scale = sqrtf(e2t * inv_gamma);
    const bool  tiny_t = (tb < 1e-6f);

    // weights -> SGPRs (uniform); c1 = t*W1[1]+b1 stays VGPR (1 SGPR/VALU rule)
    float w1a[HID], c1[HID], w20[HID], w21[HID];
#pragma unroll
    for (int i = 0; i < HID; ++i) {
        w1a[i] = to_sgpr(W1[i]);
        c1[i]  = fmaf(tb, W1[HID + i], b1[i]);
        w20[i] = to_sgpr(W2[2 * i]);
        w21[i] = to_sgpr(W2[2 * i + 1]);
    }
    const float bias0 = to_sgpr(b2[0]);
    const float bias1 = to_sgpr(b2[1]);

    const float m = valid ? mu[(size_t)b * D + d] : 0.0f;

    // ---- MLP: gelu(tanh approx) == pre * sigmoid(2u), u = 0.79788456*(pre + 0.044715 pre^3)
    float o0 = bias0, o1 = bias1;
#pragma unroll
    for (int i = 0; i < HID; ++i) {
        float pre = fmaf(m, w1a[i], c1[i]);
        float p2  = pre * pre;
        float z   = pre * fmaf(p2, -0.0713552235f, -1.5957691216f);  // -2u
        float e   = __expf(z);
        float h   = pre * __builtin_amdgcn_rcpf(1.0f + e);
        o0 = fmaf(h, w20[i], o0);
        o1 = fmaf(h, w21[i], o1);
    }

    float mu_x = fmaf(m, inv_gamma, -var_scale * o0);
    float lse  = fminf(fmaxf(o1, -10.0f), 10.0f);
    float sigma_x = fmaxf(var_scale * __expf(lse), 0.02f);
    if (tiny_t) { mu_x = 0.0f; sigma_x = 1.0f; }

    const float inv = 0.70710678118f * __builtin_amdgcn_rcpf(sigma_x);
    const float x0  = (-0.875f - mu_x) * inv;   // boundary j=1
    const float stp = 0.125f * inv;

    // cdf at 17 boundaries; 0 and 16 are exact 0/1. erf via A&S 7.1.27:
    // erf(|x|) ~= 1 - q^-4, q = 1 + a1|x| + a2 x^2 + a3 |x|^3 + a4 x^4  (|err|<=5e-4)
    // cdf = x>=0 ? 1 - r/2 : r/2, r = rcp(q^4); saturates via rcp(inf)=0.
    float cdf[KBINS + 1];
    cdf[0] = 0.0f; cdf[KBINS] = 1.0f;
#pragma unroll
    for (int j = 1; j < KBINS; ++j) {
        float x  = fmaf((float)(j - 1), stp, x0);
        float ax = fabsf(x);
        float p  = fmaf(0.078108f, ax, 0.000972f);
        p        = fmaf(p, ax, 0.230389f);
        p        = fmaf(p, ax, 0.278393f);
        float q  = fmaf(p, ax, 1.0f);
        float q2 = q * q;
        float q4 = q2 * q2;
        float hr = 0.5f * __builtin_amdgcn_rcpf(q4);
        cdf[j] = (x >= 0.0f) ? (1.0f - hr) : hr;
    }

    const bool full = (d0 + 256 <= D);   // D=49152 -> always true; tail path for safety
    if (full) {
        // stage per-element rows in LDS, then write block's 16 KB coalesced
        float4* row = (float4*)(lds + tid * 20);
#pragma unroll
        for (int s = 0; s < 4; ++s)
            row[s] = make_float4(cdf[4*s+1] - cdf[4*s],   cdf[4*s+2] - cdf[4*s+1],
                                 cdf[4*s+3] - cdf[4*s+2], cdf[4*s+4] - cdf[4*s+3]);
        __syncthreads();
        float4* og = (float4*)out + ((size_t)b * D + d0) * 4;
#pragma unroll
        for (int s = 0; s < 4; ++s) {
            int f = s * 256 + tid;          // block-local float4 index, coalesced
            int e = f >> 2;                 // source element row
            int c = (f & 3) << 2;           // word offset in row
            og[f] = *(const float4*)(lds + e * 20 + c);
        }
    } else if (valid) {
        float4* op = (float4*)(out + ((size_t)b * D + d) * (size_t)KBINS);
#pragma unroll
        for (int s = 0; s < 4; ++s)
            op[s] = make_float4(cdf[4*s+1] - cdf[4*s],   cdf[4*s+2] - cdf[4*s+1],
                                 cdf[4*s+3] - cdf[4*s+2], cdf[4*s+4] - cdf[4*s+3]);
    }
}

extern "C" void kernel_launch(void* const* d_in, const int* in_sizes, int n_in,
                              void* d_out, int out_size, void* d_ws, size_t ws_size,
                              hipStream_t stream) {
    const float* mu = (const float*)d_in[0];
    const float* t  = (const float*)d_in[1];
    const float* W1 = (const float*)d_in[2];
    const float* b1 = (const float*)d_in[3];
    const float* W2 = (const float*)d_in[4];
    const float* b2 = (const float*)d_in[5];
    float* out = (float*)d_out;

    const int B = in_sizes[1];          // t is [B,1]
    const int D = in_sizes[0] / B;      // mu is [B,D]

    dim3 block(256);
    dim3 grid((D + 255) / 256, B);
    bfn_kernel<<<grid, block, 0, stream>>>(mu, t, W1, b1, W2, b2, out, D);
}